// Round 9
// baseline (101.732 us; speedup 1.0000x reference)
//
#include <hip/hip_runtime.h>

#define N_KPS 1024
#define N_PTS 120000
#define BLOCK 256                 // 4 waves per block
#define KSPLIT 4                  // one wave per K-chunk -> 7500 waves (7.3/SIMD)
#define KCHUNK (N_KPS / KSPLIT)   // 256 ctrl points per wave

// Issue model (fits r1-r7): wall ~44 cyc/wave-iter = VALU 14 + log ~30.
// This round's decisive probe: 1:1 hybrid trans-log / VALU-poly-log. If the
// trans op runs in a parallel pipe, per-2-iter = max(56 VALU, ~30 trans) ->
// ~22us. If it blocks the issue port -> neutral, and 44 cyc/iter is the floor.
// r8's poly failed because its 3.3e-4 log2 error is multiplied by d2 (up to
// 2e4) -> absmax 18. Fix: 2-interval reduction (split mantissa at 1/sqrt2,
// centers 2^-0.75 / 2^-0.25 -> |w|<=0.19) + deg-6 Taylor -> err <= 1.8e-6
// -> output contribution <= ~0.1.
#if __has_builtin(__builtin_amdgcn_logf)
#define RAW_LOG2(x) __builtin_amdgcn_logf(x)   // bare v_log_f32 (= log2)
#else
#define RAW_LOG2(x) __log2f(x)
#endif

// Pure-VALU log2, valid for all normal floats (guaranteed by the d2 clamp).
// x = m * 2^(E-126), m in [0.5,1). Pick center c in {2^-0.75, 2^-0.25} by
// comparing m with 1/sqrt(2); w = m/c - 1 in [-0.160, 0.190).
// log2(x) = (E-126) + log2(c) + w*P(w), P = Taylor of log2(1+w)/w, deg 5.
// Truncation err = w^7/(7 ln2) <= 1.79e-6.  14 VALU ops total.
__device__ __forceinline__ float poly_log2(float x) {
    const int xi = __float_as_int(x);
    const float ef = (float)((xi >> 23) & 0xff);                      // bfe+cvt
    const float m  = __int_as_float((xi & 0x007fffff) | 0x3f000000);  // [0.5,1)
    const bool lo  = m < 0.70710678118654752f;
    const float rc = lo ? 1.68179283050742909f : 1.18920711500272107f; // 1/c
    const float lc = lo ? -126.75f : -126.25f;                 // log2(c) - 126
    const float w  = fmaf(m, rc, -1.0f);
    // b_k = (-1)^k / ((k+1) ln2), k=0..5
    float p = fmaf(-0.24044917348148720f, w, 0.28853900817779268f);
    p = fmaf(p, w, -0.36067376022224085f);
    p = fmaf(p, w,  0.48089834696297446f);
    p = fmaf(p, w, -0.72134752044448170f);
    p = fmaf(p, w,  1.44269504088896340f);
    return fmaf(w, p, ef + lc);
}

__global__ __launch_bounds__(BLOCK) void tps_warp_kernel(
    const float2* __restrict__ pts,
    const float*  __restrict__ kps,
    const float*  __restrict__ W,
    float2*       __restrict__ out)
{
    __shared__ float2 part[KSPLIT][64];

    const int lane = threadIdx.x & 63;
    // Provably wave-uniform wave id -> uniform ctrl indices -> s_load batches.
    const int wv = __builtin_amdgcn_readfirstlane(threadIdx.x) >> 6;

    const int j = blockIdx.x * 64 + lane;     // 1875*64 == 120000, exact cover
    const float2 p = pts[j];

    // Separate accumulators per path (also = pairwise summation; r5/r6's
    // 2-acc structure measured absmax 1.5-1.56 vs 2.0 single-chain).
    float zxa = 0.0f, zya = 0.0f;   // trans-path accumulator
    float zxb = 0.0f, zyb = 0.0f;   // poly-path accumulator

    const int i0 = wv * KCHUNK;
    #pragma unroll 4
    for (int g = 0; g < KCHUNK / 2; ++g) {
        const int i = i0 + 2 * g;
        // Uniform indices -> scalar loads (SGPRs), merged across the unroll.
        float kx0 = kps[2 * i],     ky0 = kps[2 * i + 1];
        float kx1 = kps[2 * i + 2], ky1 = kps[2 * i + 3];
        float wx0 = W[2 * i],       wy0 = W[2 * i + 1];
        float wx1 = W[2 * i + 2],   wy1 = W[2 * i + 3];

        // --- pair A: trans-pipe log ---
        {
            float dx = kx0 - p.x;
            float dy = ky0 - p.y;
            // +1e-37 folds the d2==0 guard: d2=0 -> v = 1e-37*log2(1e-37) ~ 0,
            // matching reference's where(l2==0,1) -> 0.5*1*ln(1)=0; also keeps
            // both log paths in the normal-float range.
            float d2 = fmaf(dy, dy, fmaf(dx, dx, 1e-37f));
            float t  = RAW_LOG2(d2);
            float v  = d2 * t;
            zxa = fmaf(v, wx0, zxa);
            zya = fmaf(v, wy0, zya);
        }
        // --- pair B: pure-VALU poly log (overlaps pair A's trans op iff the
        // trans pipe doesn't block the issue port — the thing being probed) ---
        {
            float dx = kx1 - p.x;
            float dy = ky1 - p.y;
            float d2 = fmaf(dy, dy, fmaf(dx, dx, 1e-37f));
            float t  = poly_log2(d2);
            float v  = d2 * t;
            zxb = fmaf(v, wx1, zxb);
            zyb = fmaf(v, wy1, zyb);
        }
    }

    part[wv][lane] = make_float2(zxa + zxb, zya + zyb);
    __syncthreads();

    if (wv == 0) {
        float2 a = part[0][lane];
        float2 b = part[1][lane];
        float2 c = part[2][lane];
        float2 d = part[3][lane];
        float sx = (a.x + b.x) + (c.x + d.x);
        float sy = (a.y + b.y) + (c.y + d.y);

        const float scale = 0.34657359027997264f;  // 0.5 * ln(2)
        float w1x = W[2048], w1y = W[2049];
        float wxx = W[2050], wxy = W[2051];
        float wyx = W[2052], wyy = W[2053];

        float ox = p.x + fmaf(scale, sx, fmaf(wxx, p.x, fmaf(wyx, p.y, w1x)));
        float oy = p.y + fmaf(scale, sy, fmaf(wxy, p.x, fmaf(wyy, p.y, w1y)));
        out[j] = make_float2(ox, oy);
    }
}

extern "C" void kernel_launch(void* const* d_in, const int* in_sizes, int n_in,
                              void* d_out, int out_size, void* d_ws, size_t ws_size,
                              hipStream_t stream) {
    const float* pts = (const float*)d_in[0];   // [120000, 2]
    const float* kps = (const float*)d_in[1];   // [1024, 2]
    const float* W   = (const float*)d_in[2];   // [1027, 2]
    float* out = (float*)d_out;                 // [120000, 2]

    const int grid = N_PTS / 64;                // 1875, exact
    tps_warp_kernel<<<grid, BLOCK, 0, stream>>>(
        (const float2*)pts, kps, W, (float2*)out);
}